// Round 1
// baseline (113.539 us; speedup 1.0000x reference)
//
#include <hip/hip_runtime.h>
#include <hip/hip_bf16.h>

#define NB 8
#define NS 4096
#define NE 16
#define ND 128
#define NG 256

typedef float  f32x4 __attribute__((ext_vector_type(4)));
typedef short  s16x8 __attribute__((ext_vector_type(8)));
typedef short  s16x4 __attribute__((ext_vector_type(4)));

#define SCALE_LOG2E 0.12752749570528832f  /* log2(e)/sqrt(128) */
#define NEGF (-1e30f)

__device__ __forceinline__ short f2bf(float f) {
  unsigned u = __builtin_bit_cast(unsigned, f);
  unsigned r = (u + 0x7fffu + ((u >> 16) & 1u)) >> 16;  // RNE
  return (short)r;
}

// row-wise softmax over MAXT col-tiles held in regs; rows = hi*4+r, cols spread
// over 16 lanes (l&15) x MAXT tiles. Normalizes s in place to probabilities.
template<int MAXT>
__device__ __forceinline__ void softmax_norm(f32x4 (&s)[MAXT]) {
  #pragma unroll
  for (int r = 0; r < 4; ++r) {
    float m = NEGF;
    #pragma unroll
    for (int ct = 0; ct < MAXT; ++ct) m = fmaxf(m, s[ct][r]);
    m = fmaxf(m, __shfl_xor(m, 1));
    m = fmaxf(m, __shfl_xor(m, 2));
    m = fmaxf(m, __shfl_xor(m, 4));
    m = fmaxf(m, __shfl_xor(m, 8));
    float sum = 0.f;
    #pragma unroll
    for (int ct = 0; ct < MAXT; ++ct) {
      float p = exp2f((s[ct][r] - m) * SCALE_LOG2E);
      s[ct][r] = p;
      sum += p;
    }
    sum += __shfl_xor(sum, 1);
    sum += __shfl_xor(sum, 2);
    sum += __shfl_xor(sum, 4);
    sum += __shfl_xor(sum, 8);
    float rinv = 1.0f / sum;
    #pragma unroll
    for (int ct = 0; ct < MAXT; ++ct) s[ct][r] *= rinv;
  }
}

// PV for one 16-row tile; kvb holds swizzled V^T [d][h]; plw = per-wave P chunk.
template<int MAXT>
__device__ __forceinline__ void pv_store(const f32x4 (&s)[MAXT], int RT,
                                         const char* kvb, char* plw,
                                         float* outbase, int c15, int hi) {
  f32x4 o[8];
  #pragma unroll
  for (int dt = 0; dt < 8; ++dt) o[dt] = f32x4{0.f, 0.f, 0.f, 0.f};

  #pragma unroll
  for (int hc = 0; hc < MAXT / 4; ++hc) {
    if (hc * 4 <= RT) {  // wave-uniform
      // write normalized P chunk [16 rows][64 cols] bf16, swizzled
      #pragma unroll
      for (int cr = 0; cr < 4; ++cr) {
        const int ct = hc * 4 + cr;
        #pragma unroll
        for (int r = 0; r < 4; ++r) {
          float pv = (ct <= RT) ? s[ct][r] : 0.0f;
          int gl = hi * 4 + r;
          int byte = gl * 128 + (((cr * 16 + c15) * 2) ^ ((gl & 7) << 4));
          *(short*)(plw + byte) = f2bf(pv);
        }
      }
      // in-wave DS ops are in-order: write->read RAW is safe
      #pragma unroll
      for (int kb = 0; kb < 2; ++kb) {
        int abyte = c15 * 128 + (((kb * 32 + hi * 8) * 2) ^ ((c15 & 7) << 4));
        s16x8 pf = *(const s16x8*)(plw + abyte);
        #pragma unroll
        for (int dt = 0; dt < 8; ++dt) {
          int d = dt * 16 + c15;
          int hof = hc * 64 + kb * 32 + hi * 8;
          int vbyte = d * 512 + ((hof * 2) ^ ((d & 7) << 4));
          s16x8 vf = *(const s16x8*)(kvb + vbyte);
          o[dt] = __builtin_amdgcn_mfma_f32_16x16x32_bf16(pf, vf, o[dt], 0, 0, 0);
        }
      }
    }
  }
  #pragma unroll
  for (int dt = 0; dt < 8; ++dt) {
    #pragma unroll
    for (int r = 0; r < 4; ++r)
      outbase[(size_t)(hi * 4 + r) * ND + dt * 16 + c15] = o[dt][r];
  }
}

__global__ __launch_bounds__(256, 1) void sattn_kernel(
    const float* __restrict__ Qg, const float* __restrict__ Kg,
    const float* __restrict__ Vg, const float* __restrict__ RM,
    float* __restrict__ Out) {
  __shared__ int idx[NG];
  __shared__ __align__(16) short kv[NG * ND];      // 64KB: K[h][d] then V^T[d][h]
  __shared__ __align__(16) short plds[4][16 * 64]; // 8KB per-wave P chunks

  const int tid = threadIdx.x;
  const int lane = tid & 63;
  const int w = tid >> 6;
  const int c15 = lane & 15;
  const int hi = lane >> 4;

  const int bid = blockIdx.x;
  const int be = bid >> 1;     // b*16+e
  const int jhalf = bid & 1;
  const int b = be >> 4;
  const int e = be & 15;

  // ---- phase 0: stable gather index list for expert e ----
  {
    int* cnt = (int*)kv;
    const float* rmb = RM + (size_t)b * NS * NE + e;
    unsigned mbits = 0;
    int cloc = 0;
    #pragma unroll
    for (int i = 0; i < 16; ++i) {
      bool m = rmb[(size_t)(tid * 16 + i) * NE] > 0.5f;
      mbits |= (m ? 1u : 0u) << i;
      cloc += m ? 1 : 0;
    }
    cnt[tid] = cloc;
    __syncthreads();
    for (int off = 1; off < 256; off <<= 1) {   // Hillis-Steele inclusive scan
      int v = cnt[tid];
      int add = (tid >= off) ? cnt[tid - off] : 0;
      __syncthreads();
      cnt[tid] = v + add;
      __syncthreads();
    }
    int pos = cnt[tid] - cloc;  // exclusive
    for (int i = 0; i < 16; ++i)
      if (mbits & (1u << i)) idx[pos++] = tid * 16 + i;
    __syncthreads();
  }

  // ---- phase 1: stage K rows (gathered) as bf16, XOR-swizzled ----
  {
    const int row_off = tid >> 5;   // 0..7
    const int c4 = tid & 31;        // float4 within row
    const float* kbase = Kg + (size_t)b * NS * ND;
    #pragma unroll 4
    for (int r0 = 0; r0 < NG; r0 += 8) {
      int h = r0 + row_off;
      int tok = idx[h];
      float4 v = *(const float4*)(kbase + (size_t)tok * ND + c4 * 4);
      s16x4 p;
      p[0] = f2bf(v.x); p[1] = f2bf(v.y); p[2] = f2bf(v.z); p[3] = f2bf(v.w);
      int byte = h * 256 + ((c4 * 8) ^ ((h & 7) << 4));
      *(s16x4*)((char*)kv + byte) = p;
    }
  }

  // ---- Q fragments straight from global (gathered rows) ----
  const int pairIdx = jhalf * 4 + w;  // 0..7
  const int RTa = pairIdx;            // <= 7
  const int RTb = 15 - pairIdx;       // >= 8

  s16x8 qf[2][4];
  #pragma unroll
  for (int t = 0; t < 2; ++t) {
    const int RT = t ? RTb : RTa;
    const int g = RT * 16 + c15;     // A-frag row = lane&15
    const float* qrow = Qg + ((size_t)b * NS + idx[g]) * ND;
    #pragma unroll
    for (int kb = 0; kb < 4; ++kb) {
      const int d0 = kb * 32 + hi * 8;
      float4 x = *(const float4*)(qrow + d0);
      float4 y = *(const float4*)(qrow + d0 + 4);
      s16x8 q;
      q[0] = f2bf(x.x); q[1] = f2bf(x.y); q[2] = f2bf(x.z); q[3] = f2bf(x.w);
      q[4] = f2bf(y.x); q[5] = f2bf(y.y); q[6] = f2bf(y.z); q[7] = f2bf(y.w);
      qf[t][kb] = q;
    }
  }
  __syncthreads();  // K staged

  // ---- S phase: scores for both row-tiles, kept in registers ----
  f32x4 sA[8], sB[16];
  #pragma unroll
  for (int ct = 0; ct < 8; ++ct) {
    f32x4 acc = f32x4{0.f, 0.f, 0.f, 0.f};
    if (ct <= RTa) {
      #pragma unroll
      for (int kb = 0; kb < 4; ++kb) {
        int h = ct * 16 + c15;  // B-frag col = lane&15
        int byte = h * 256 + (((kb * 32 + hi * 8) * 2) ^ ((h & 7) << 4));
        s16x8 kf = *(const s16x8*)((const char*)kv + byte);
        acc = __builtin_amdgcn_mfma_f32_16x16x32_bf16(qf[0][kb], kf, acc, 0, 0, 0);
      }
      if (ct == RTa) {  // diagonal tile causal mask: col>row -> -inf
        #pragma unroll
        for (int r = 0; r < 4; ++r)
          if (c15 > hi * 4 + r) acc[r] = NEGF;
      }
    } else {
      acc = f32x4{NEGF, NEGF, NEGF, NEGF};
    }
    sA[ct] = acc;
  }
  #pragma unroll
  for (int ct = 0; ct < 16; ++ct) {
    f32x4 acc = f32x4{0.f, 0.f, 0.f, 0.f};
    if (ct <= RTb) {
      #pragma unroll
      for (int kb = 0; kb < 4; ++kb) {
        int h = ct * 16 + c15;
        int byte = h * 256 + (((kb * 32 + hi * 8) * 2) ^ ((h & 7) << 4));
        s16x8 kf = *(const s16x8*)((const char*)kv + byte);
        acc = __builtin_amdgcn_mfma_f32_16x16x32_bf16(qf[1][kb], kf, acc, 0, 0, 0);
      }
      if (ct == RTb) {
        #pragma unroll
        for (int r = 0; r < 4; ++r)
          if (c15 > hi * 4 + r) acc[r] = NEGF;
      }
    } else {
      acc = f32x4{NEGF, NEGF, NEGF, NEGF};
    }
    sB[ct] = acc;
  }

  softmax_norm<8>(sA);
  softmax_norm<16>(sB);

  __syncthreads();  // everyone done reading K from LDS

  // ---- stage V^T (overwrite kv): element (d,h) at d*512 + ((h*2)^((d&7)<<4)) ----
  {
    const int row = tid;  // h: 64 consecutive rows per wave -> 2-way LDS writes (free)
    const float* vrow = Vg + ((size_t)b * NS + idx[row]) * ND;
    #pragma unroll 4
    for (int p4 = 0; p4 < 32; ++p4) {
      float4 v = *(const float4*)(vrow + p4 * 4);
      #pragma unroll
      for (int i = 0; i < 4; ++i) {
        int d = p4 * 4 + i;
        float val = (i == 0) ? v.x : (i == 1) ? v.y : (i == 2) ? v.z : v.w;
        int byte = d * 512 + ((row * 2) ^ ((d & 7) << 4));
        *(short*)((char*)kv + byte) = f2bf(val);
      }
    }
  }
  __syncthreads();  // V^T staged

  // ---- PV + store ----
  char* plw = (char*)plds[w];
  float* oa = Out + ((size_t)be * NG + RTa * 16) * ND;
  pv_store<8>(sA, RTa, (const char*)kv, plw, oa, c15, hi);
  float* ob = Out + ((size_t)be * NG + RTb * 16) * ND;
  pv_store<16>(sB, RTb, (const char*)kv, plw, ob, c15, hi);
}

extern "C" void kernel_launch(void* const* d_in, const int* in_sizes, int n_in,
                              void* d_out, int out_size, void* d_ws, size_t ws_size,
                              hipStream_t stream) {
  const float* Q  = (const float*)d_in[0];
  const float* K  = (const float*)d_in[1];
  const float* V  = (const float*)d_in[2];
  const float* RM = (const float*)d_in[3];
  // d_in[4] = mask: causal triu(k=1), hardcoded in-kernel
  float* Out = (float*)d_out;
  sattn_kernel<<<dim3(NB * NE * 2), dim3(256), 0, stream>>>(Q, K, V, RM, Out);
}